// Round 9
// baseline (200.813 us; speedup 1.0000x reference)
//
#include <hip/hip_runtime.h>
#include <math.h>

#define NN 50000
#define NE 800000
#define CD 128
#define NBKT 49          // coarse buckets of 1024 dst nodes (49*1024 >= 50000)
#define CAP 24576        // bucket capacity (mean 16327, sd ~127: +64 sd)
#define SLICE 4096       // edges per binning block
#define EBLK 196         // binning blocks (196*4096 >= NE)
#define CASTB 2048       // cast blocks
#define NBLK2 1563       // fused blocks of 32 nodes (1563*32 >= NN)

typedef __attribute__((ext_vector_type(8))) short short8;
typedef __attribute__((ext_vector_type(4))) float f32x4;

// ---------------- helpers ----------------

__device__ inline unsigned pack2bf(float lo, float hi) {
    unsigned a = __float_as_uint(lo), b = __float_as_uint(hi);
    a = (a + 0x7fffu + ((a >> 16) & 1u)) >> 16;
    b = (b + 0x7fffu + ((b >> 16) & 1u)) & 0xffff0000u;
    return a | b;
}

__device__ inline unsigned short f2bf(float f) {
    unsigned u = __float_as_uint(f);
    return (unsigned short)((u + 0x7fffu + ((u >> 16) & 1u)) >> 16);
}

__device__ inline void fmax8(float* m, uint4 v) {
    m[0] = fmaxf(m[0], __uint_as_float(v.x << 16));
    m[1] = fmaxf(m[1], __uint_as_float(v.x & 0xffff0000u));
    m[2] = fmaxf(m[2], __uint_as_float(v.y << 16));
    m[3] = fmaxf(m[3], __uint_as_float(v.y & 0xffff0000u));
    m[4] = fmaxf(m[4], __uint_as_float(v.z << 16));
    m[5] = fmaxf(m[5], __uint_as_float(v.z & 0xffff0000u));
    m[6] = fmaxf(m[6], __uint_as_float(v.w << 16));
    m[7] = fmaxf(m[7], __uint_as_float(v.w & 0xffff0000u));
}

// ---------------- prep: 2-pass coarse binning (49 atomics/block) + casts ------
// Edge blocks: pass A = LDS histogram of a 4096-edge slice over 49 buckets
// (bin = dst>>10); 49 global atomicAdds reserve contiguous runs; pass B
// re-reads the slice (L2-hot) and places (src<<10)|(dst&1023) via LDS cursors
// -> ~84-word contiguous runs per (block,bin), line-dense writes.
// Bucket overflow (P ~ 0) -> global list, scanned by fused_k: never drops edges.
// Cast blocks: x -> bf16 (xb), W -> transposed bf16 wt[n][k].

__global__ __launch_bounds__(256) void prep5_k(const int* __restrict__ ei,
                                               const float* __restrict__ x,
                                               const float* __restrict__ W,
                                               int* __restrict__ cur,
                                               int* __restrict__ ovfn,
                                               unsigned* __restrict__ ovf,
                                               unsigned* __restrict__ csr,
                                               unsigned* __restrict__ xb,
                                               unsigned short* __restrict__ wt) {
    int b = blockIdx.x;
    int t = threadIdx.x;
    if (b < EBLK) {
        __shared__ int hist[64];
        __shared__ int curs[64];
        int e0 = b * SLICE;
        int e1 = min(NE, e0 + SLICE);
        if (t < 64) hist[t] = 0;
        __syncthreads();
        for (int e = e0 + t; e < e1; e += 256)
            atomicAdd(&hist[((unsigned)ei[NE + e]) >> 10], 1);
        __syncthreads();
        if (t < NBKT) curs[t] = atomicAdd(&cur[t], hist[t]);
        __syncthreads();
        for (int e = e0 + t; e < e1; e += 256) {
            int d = ei[NE + e];
            int s = ei[e];
            int bin = ((unsigned)d) >> 10;
            int p = atomicAdd(&curs[bin], 1);
            if (p < CAP) {
                csr[(size_t)bin * CAP + p] = ((unsigned)s << 10) | (unsigned)(d & 1023);
            } else {
                int op = atomicAdd(ovfn, 1);
                ovf[op] = ((unsigned)s << 16) | (unsigned)d;
            }
        }
    } else {
        int tid0 = (b - EBLK) * 256 + t;
        for (int i = tid0; i < NN * CD / 4; i += CASTB * 256) {
            float4 v = ((const float4*)x)[i];
            uint2 r;
            r.x = pack2bf(v.x, v.y);
            r.y = pack2bf(v.z, v.w);
            ((uint2*)xb)[i] = r;
        }
        for (int i = tid0; i < 2 * CD * CD; i += CASTB * 256) {
            int n = i >> 8, k = i & 255;
            wt[(size_t)n * 256 + k] = f2bf(W[(size_t)k * 128 + n]);
        }
    }
}

// ---------------- fused gather + GEMM: one block = 32 output rows, 4 waves ----
// Phase 0: stream this block's coarse bucket (coalesced, L2-resident: 32 blocks
//          share each bucket), filter for our 32 nodes -> per-node LDS lists.
// Phase 1: 16 quarters x 2 nodes; 8 row-loads in flight per quarter;
//          maxdiff bf16 -> LDS A-tile.
// Phase 2: MFMA GEMM (verified round-3/8 layout); wave w = row-tile x col-half.

__global__ __launch_bounds__(256) void fused_k(const unsigned* __restrict__ xb,
                                               const int* __restrict__ cur,
                                               const int* __restrict__ ovfn,
                                               const unsigned* __restrict__ ovf,
                                               const unsigned* __restrict__ csr,
                                               const short* __restrict__ wt,
                                               const float* __restrict__ bias,
                                               float* __restrict__ out) {
    __shared__ unsigned short idx[32][72];   // 64 usable entries; 144 B rows (16B-aligned)
    __shared__ unsigned short amx[32][136];  // maxdiff bf16 A-tile
    __shared__ int lcnt[32];
    __shared__ int spill[512];               // per-node-cap overflow (normally empty)
    __shared__ int spn;

    int t = threadIdx.x;
    int B = blockIdx.x;
    int qb = B >> 5;                         // coarse bucket
    int sub = B & 31;                        // which 32-node slice of the bucket
    int nbase = B * 32;

    if (t < 32) lcnt[t] = 0;
    if (t == 32) spn = 0;
    __syncthreads();

    // ---- phase 0: filter bucket stream into per-node lists ----
    int cnt = min(cur[qb], CAP);
    const unsigned* base = csr + (size_t)qb * CAP;
    for (int i = t; i < cnt; i += 256) {
        unsigned w = base[i];
        if ((int)((w >> 5) & 31) == sub) {
            int ln = (int)(w & 31u);
            int s = (int)(w >> 10);
            int pos = atomicAdd(&lcnt[ln], 1);
            if (pos < 64) idx[ln][pos] = (unsigned short)s;
            else { int sp = atomicAdd(&spn, 1); if (sp < 512) spill[sp] = (s << 6) | ln; }
        }
    }
    int ovN = min(ovfn[0], NE);              // bucket overflow (normally 0)
    for (int i = t; i < ovN; i += 256) {
        unsigned w = ovf[i];
        int d = (int)(w & 0xffffu);
        if ((d >> 5) == B) {
            int ln = d & 31;
            int s = (int)(w >> 16);
            int pos = atomicAdd(&lcnt[ln], 1);
            if (pos < 64) idx[ln][pos] = (unsigned short)s;
            else { int sp = atomicAdd(&spn, 1); if (sp < 512) spill[sp] = (s << 6) | ln; }
        }
    }
    __syncthreads();

    // ---- phase 1: segment max, 2 nodes per 16-lane quarter ----
    int w = t >> 6, lane = t & 63;
    int q = lane >> 4, c = lane & 15;
    int sN = min(spn, 512);
#pragma unroll 1
    for (int j = 0; j < 2; j++) {
        int ln = w * 8 + j * 4 + q;
        int node = nbase + ln;
        int lc = lcnt[ln];
        int lim = min(lc, 64);
        float m[8];
#pragma unroll
        for (int i = 0; i < 8; i++) m[i] = -INFINITY;

        for (int bb = 0; bb < lim; bb += 8) {
            uint4 pk = *(const uint4*)&idx[ln][bb];
            int s0 = (int)(pk.x & 0xffffu), s1 = (int)(pk.x >> 16);
            int s2 = (int)(pk.y & 0xffffu), s3 = (int)(pk.y >> 16);
            int s4 = (int)(pk.z & 0xffffu), s5 = (int)(pk.z >> 16);
            int s6 = (int)(pk.w & 0xffffu), s7 = (int)(pk.w >> 16);
            if (bb + 8 <= lim) {              // fast path: 8 loads in flight
                fmax8(m, *(const uint4*)(xb + (size_t)s0 * 64 + c * 4));
                fmax8(m, *(const uint4*)(xb + (size_t)s1 * 64 + c * 4));
                fmax8(m, *(const uint4*)(xb + (size_t)s2 * 64 + c * 4));
                fmax8(m, *(const uint4*)(xb + (size_t)s3 * 64 + c * 4));
                fmax8(m, *(const uint4*)(xb + (size_t)s4 * 64 + c * 4));
                fmax8(m, *(const uint4*)(xb + (size_t)s5 * 64 + c * 4));
                fmax8(m, *(const uint4*)(xb + (size_t)s6 * 64 + c * 4));
                fmax8(m, *(const uint4*)(xb + (size_t)s7 * 64 + c * 4));
            } else {
                if (bb + 0 < lim) fmax8(m, *(const uint4*)(xb + (size_t)s0 * 64 + c * 4));
                if (bb + 1 < lim) fmax8(m, *(const uint4*)(xb + (size_t)s1 * 64 + c * 4));
                if (bb + 2 < lim) fmax8(m, *(const uint4*)(xb + (size_t)s2 * 64 + c * 4));
                if (bb + 3 < lim) fmax8(m, *(const uint4*)(xb + (size_t)s3 * 64 + c * 4));
                if (bb + 4 < lim) fmax8(m, *(const uint4*)(xb + (size_t)s4 * 64 + c * 4));
                if (bb + 5 < lim) fmax8(m, *(const uint4*)(xb + (size_t)s5 * 64 + c * 4));
                if (bb + 6 < lim) fmax8(m, *(const uint4*)(xb + (size_t)s6 * 64 + c * 4));
                if (bb + 7 < lim) fmax8(m, *(const uint4*)(xb + (size_t)s7 * 64 + c * 4));
            }
        }
        for (int i = 0; i < sN; i++) {        // per-node-cap spill (normally 0)
            int sw = spill[i];
            if ((sw & 63) == ln)
                fmax8(m, *(const uint4*)(xb + (size_t)(sw >> 6) * 64 + c * 4));
        }
        uint4 r = make_uint4(0u, 0u, 0u, 0u);
        if (lc > 0) {                         // implies node < NN
            uint4 xd = *(const uint4*)(xb + (size_t)node * 64 + c * 4);
            float d0 = m[0] - __uint_as_float(xd.x << 16);
            float d1 = m[1] - __uint_as_float(xd.x & 0xffff0000u);
            float d2 = m[2] - __uint_as_float(xd.y << 16);
            float d3 = m[3] - __uint_as_float(xd.y & 0xffff0000u);
            float d4 = m[4] - __uint_as_float(xd.z << 16);
            float d5 = m[5] - __uint_as_float(xd.z & 0xffff0000u);
            float d6 = m[6] - __uint_as_float(xd.w << 16);
            float d7 = m[7] - __uint_as_float(xd.w & 0xffff0000u);
            r.x = pack2bf(d0, d1);
            r.y = pack2bf(d2, d3);
            r.z = pack2bf(d4, d5);
            r.w = pack2bf(d6, d7);
        }
        *(uint4*)&amx[ln][c * 8] = r;
    }
    __syncthreads();

    // ---- phase 2: MFMA GEMM (verified layout) ----
    int mm = lane & 15, g4 = lane >> 4;
    int rt = w & 1, ch = w >> 1;
    int r0 = nbase + rt * 16;
    int row = r0 + mm;
    bool rowok = row < NN;

    f32x4 acc[4];
#pragma unroll
    for (int ct = 0; ct < 4; ct++) {
        float bv = bias[ch * 64 + ct * 16 + mm];
        acc[ct] = (f32x4){bv, bv, bv, bv};
    }

    const short* xbs = (const short*)xb;
#pragma unroll
    for (int kc = 0; kc < 8; kc++) {
        int k0 = kc * 32;
        short8 a;
        if (kc < 4) {
            a = (short8){0, 0, 0, 0, 0, 0, 0, 0};
            if (rowok) a = *(const short8*)(xbs + (size_t)row * 128 + k0 + g4 * 8);
        } else {
            a = *(const short8*)&amx[rt * 16 + mm][(k0 - 128) + g4 * 8];
        }
#pragma unroll
        for (int ct = 0; ct < 4; ct++) {
            short8 bb = *(const short8*)(wt + (size_t)(ch * 64 + ct * 16 + mm) * 256 + k0 + g4 * 8);
            acc[ct] = __builtin_amdgcn_mfma_f32_16x16x32_bf16(a, bb, acc[ct], 0, 0, 0);
        }
    }

#pragma unroll
    for (int ct = 0; ct < 4; ct++) {
#pragma unroll
        for (int i = 0; i < 4; i++) {
            int rr = r0 + g4 * 4 + i;
            if (rr < NN) out[(size_t)rr * 128 + ch * 64 + ct * 16 + mm] = acc[ct][i];
        }
    }
}

// ---------------- launch ----------------

extern "C" void kernel_launch(void* const* d_in, const int* in_sizes, int n_in,
                              void* d_out, int out_size, void* d_ws, size_t ws_size,
                              hipStream_t stream) {
    const float* x = (const float*)d_in[0];
    const int* ei = (const int*)d_in[1];     // (2, E): [0..E)=src, [E..2E)=dst
    const float* W = (const float*)d_in[2];  // (256, 128) row-major
    const float* bias = (const float*)d_in[3];
    float* out = (float*)d_out;

    // Workspace layout (ints). Total = 5,220,688 ints = 20.88 MB.
    int* wsi = (int*)d_ws;
    int* cur   = wsi;                               // 64 ints (49 used)
    int* ovfn  = wsi + 64;                          // 16 ints (1 used)
    unsigned* ovf = (unsigned*)(wsi + 80);          // 800,000 (cap NE: never drops)
    unsigned* csr = (unsigned*)(wsi + 800080);      // NBKT*CAP = 1,204,224
    unsigned* xb  = (unsigned*)(wsi + 2004304);     // 3,200,000 (16B-aligned)
    unsigned short* wt = (unsigned short*)(wsi + 5204304);  // 32768 ush = 16384 ints

    hipMemsetAsync(cur, 0, 80 * sizeof(int), stream);  // cur + ovfn

    prep5_k<<<EBLK + CASTB, 256, 0, stream>>>(ei, x, W, cur, ovfn, ovf, csr, xb, wt);
    fused_k<<<NBLK2, 256, 0, stream>>>(xb, cur, ovfn, ovf, csr, (const short*)wt,
                                       bias, out);
}

// Round 10
// 199.867 us; speedup vs baseline: 1.0047x; 1.0047x over previous
//
#include <hip/hip_runtime.h>
#include <math.h>

#define NN 50000
#define NE 800000
#define CD 128
#define NBKT 49          // coarse buckets of 1024 dst nodes
#define CAP 24576        // bucket capacity (mean 16327; +64 sd)
#define SLICE 4096       // edges per binning block
#define EBLK 196         // binning blocks
#define CASTB 2048       // cast blocks
#define NBLK2 1563       // fused blocks of 32 nodes
#define SUBCAP 768       // sub-bin capacity (mean 510, sd 22.6: +11 sd)

typedef __attribute__((ext_vector_type(8))) short short8;
typedef __attribute__((ext_vector_type(4))) float f32x4;

// ---------------- helpers ----------------

__device__ inline unsigned pack2bf(float lo, float hi) {
    unsigned a = __float_as_uint(lo), b = __float_as_uint(hi);
    a = (a + 0x7fffu + ((a >> 16) & 1u)) >> 16;
    b = (b + 0x7fffu + ((b >> 16) & 1u)) & 0xffff0000u;
    return a | b;
}

__device__ inline unsigned short f2bf(float f) {
    unsigned u = __float_as_uint(f);
    return (unsigned short)((u + 0x7fffu + ((u >> 16) & 1u)) >> 16);
}

__device__ inline void fmax2(float& a, float& b, unsigned v) {
    a = fmaxf(a, __uint_as_float(v << 16));
    b = fmaxf(b, __uint_as_float(v & 0xffff0000u));
}

// ---------------- prep: 2-pass coarse binning (49 atomics/block) + casts ------
// (verbatim round-9 prep5 — proven correct & fast)

__global__ __launch_bounds__(256) void prep5_k(const int* __restrict__ ei,
                                               const float* __restrict__ x,
                                               const float* __restrict__ W,
                                               int* __restrict__ cur,
                                               int* __restrict__ ovfn,
                                               unsigned* __restrict__ ovf,
                                               unsigned* __restrict__ csr,
                                               unsigned* __restrict__ xb,
                                               unsigned short* __restrict__ wt) {
    int b = blockIdx.x;
    int t = threadIdx.x;
    if (b < EBLK) {
        __shared__ int hist[64];
        __shared__ int curs[64];
        int e0 = b * SLICE;
        int e1 = min(NE, e0 + SLICE);
        if (t < 64) hist[t] = 0;
        __syncthreads();
        for (int e = e0 + t; e < e1; e += 256)
            atomicAdd(&hist[((unsigned)ei[NE + e]) >> 10], 1);
        __syncthreads();
        if (t < NBKT) curs[t] = atomicAdd(&cur[t], hist[t]);
        __syncthreads();
        for (int e = e0 + t; e < e1; e += 256) {
            int d = ei[NE + e];
            int s = ei[e];
            int bin = ((unsigned)d) >> 10;
            int p = atomicAdd(&curs[bin], 1);
            if (p < CAP) {
                csr[(size_t)bin * CAP + p] = ((unsigned)s << 10) | (unsigned)(d & 1023);
            } else {
                int op = atomicAdd(ovfn, 1);
                ovf[op] = ((unsigned)s << 16) | (unsigned)d;
            }
        }
    } else {
        int tid0 = (b - EBLK) * 256 + t;
        for (int i = tid0; i < NN * CD / 4; i += CASTB * 256) {
            float4 v = ((const float4*)x)[i];
            uint2 r;
            r.x = pack2bf(v.x, v.y);
            r.y = pack2bf(v.z, v.w);
            ((uint2*)xb)[i] = r;
        }
        for (int i = tid0; i < 2 * CD * CD; i += CASTB * 256) {
            int n = i >> 8, k = i & 255;
            wt[(size_t)n * 256 + k] = f2bf(W[(size_t)k * 128 + n]);
        }
    }
}

// ---------------- rebin: bucket -> exact 32-node sub-lists --------------------
// 49 buckets x 8 slices. LDS histogram (32 bins) + 32 global atomicAdds/block
// (12.5K total) + line-dense placement. Entry: (src << 5) | (dst & 31).

__global__ __launch_bounds__(256) void rebin_k(const int* __restrict__ cur,
                                               const unsigned* __restrict__ csr,
                                               int* __restrict__ subcur,
                                               int* __restrict__ ovfn2,
                                               unsigned* __restrict__ ovf2,
                                               unsigned* __restrict__ csr2) {
    __shared__ int hist[32];
    __shared__ int curs[32];
    int b = blockIdx.x, t = threadIdx.x;
    int q = b >> 3, s = b & 7;
    int cnt = min(cur[q], CAP);
    int i0 = (cnt * s) >> 3, i1 = (cnt * (s + 1)) >> 3;
    if (t < 32) hist[t] = 0;
    __syncthreads();
    const unsigned* base = csr + (size_t)q * CAP;
    for (int i = i0 + t; i < i1; i += 256)
        atomicAdd(&hist[(base[i] >> 5) & 31], 1);
    __syncthreads();
    if (t < 32) curs[t] = atomicAdd(&subcur[q * 32 + t], hist[t]);
    __syncthreads();
    for (int i = i0 + t; i < i1; i += 256) {
        unsigned w = base[i];
        int sub = (int)((w >> 5) & 31u);
        int p = atomicAdd(&curs[sub], 1);
        if (p < SUBCAP) {
            csr2[(size_t)(q * 32 + sub) * SUBCAP + p] = ((w >> 10) << 5) | (w & 31u);
        } else {
            int op = atomicAdd(ovfn2, 1);
            ovf2[op] = ((w >> 10) << 16) | (unsigned)(q * 1024 + (int)(w & 1023u));
        }
    }
}

// ---------------- fused gather + GEMM: one block = 32 output rows -------------
// Phase 0: read own sub-list (~512 words, coalesced) -> per-node LDS lists.
// Phase 1: 4 column-stripes of 32 channels. Each stripe of xb is 3.2 MB ->
//          L2-resident per XCD -> MSHR-limited throughput at L2 (not LLC)
//          latency. 8 dword row-loads in flight per quarter.
// Phase 2: MFMA GEMM (verified round-3/8/9 layout).

__global__ __launch_bounds__(256) void fused_k(const unsigned* __restrict__ xb,
                                               const int* __restrict__ subcur,
                                               const int* __restrict__ ovfn,
                                               const unsigned* __restrict__ ovf,
                                               const int* __restrict__ ovfn2,
                                               const unsigned* __restrict__ ovf2,
                                               const unsigned* __restrict__ csr2,
                                               const short* __restrict__ wt,
                                               const float* __restrict__ bias,
                                               float* __restrict__ out) {
    __shared__ unsigned short idx[32][72];   // 64 entries; 144 B rows (16B-aligned)
    __shared__ unsigned short amx[32][136];  // maxdiff bf16 A-tile, 272 B pitch
    __shared__ int lcnt[32];
    __shared__ int spill[512];               // per-node-cap overflow (normally empty)
    __shared__ int spn;

    int t = threadIdx.x;
    int B = blockIdx.x;
    int nbase = B * 32;

    if (t < 32) lcnt[t] = 0;
    if (t == 32) spn = 0;
    __syncthreads();

    // ---- phase 0: own sub-list -> per-node lists ----
    int cnt = min(subcur[B], SUBCAP);
    const unsigned* base = csr2 + (size_t)B * SUBCAP;
    for (int i = t; i < cnt; i += 256) {
        unsigned w = base[i];
        int ln = (int)(w & 31u);
        int s = (int)(w >> 5);
        int pos = atomicAdd(&lcnt[ln], 1);
        if (pos < 64) idx[ln][pos] = (unsigned short)s;
        else { int sp = atomicAdd(&spn, 1); if (sp < 512) spill[sp] = (s << 6) | ln; }
    }
    int ovN = min(ovfn[0], NE);              // bucket overflow (normally 0)
    for (int i = t; i < ovN; i += 256) {
        unsigned w = ovf[i];
        int d = (int)(w & 0xffffu);
        if ((d >> 5) == B) {
            int ln = d & 31;
            int s = (int)(w >> 16);
            int pos = atomicAdd(&lcnt[ln], 1);
            if (pos < 64) idx[ln][pos] = (unsigned short)s;
            else { int sp = atomicAdd(&spn, 1); if (sp < 512) spill[sp] = (s << 6) | ln; }
        }
    }
    int ovN2 = min(ovfn2[0], NE);            // sub-bin overflow (normally 0)
    for (int i = t; i < ovN2; i += 256) {
        unsigned w = ovf2[i];
        int d = (int)(w & 0xffffu);
        if ((d >> 5) == B) {
            int ln = d & 31;
            int s = (int)(w >> 16);
            int pos = atomicAdd(&lcnt[ln], 1);
            if (pos < 64) idx[ln][pos] = (unsigned short)s;
            else { int sp = atomicAdd(&spn, 1); if (sp < 512) spill[sp] = (s << 6) | ln; }
        }
    }
    __syncthreads();

    // ---- phase 1: segment max over 4 column stripes of 32 channels ----
    int w = t >> 6, lane = t & 63;
    int q4 = lane >> 4, c = lane & 15;
    int sN = min(spn, 512);
#pragma unroll 1
    for (int cb = 0; cb < 4; cb++) {
        const unsigned* xcb = xb + cb * 16 + c;   // lane's dword within the stripe
#pragma unroll 1
        for (int j = 0; j < 2; j++) {
            int ln = w * 8 + j * 4 + q4;
            int node = nbase + ln;
            int lc = lcnt[ln];
            int lim = min(lc, 64);
            float m0 = -INFINITY, m1 = -INFINITY;

            for (int bb = 0; bb < lim; bb += 8) {
                uint4 pk = *(const uint4*)&idx[ln][bb];
                int s0 = (int)(pk.x & 0xffffu), s1 = (int)(pk.x >> 16);
                int s2 = (int)(pk.y & 0xffffu), s3 = (int)(pk.y >> 16);
                int s4 = (int)(pk.z & 0xffffu), s5 = (int)(pk.z >> 16);
                int s6 = (int)(pk.w & 0xffffu), s7 = (int)(pk.w >> 16);
                if (bb + 8 <= lim) {          // fast path: 8 dword loads in flight
                    unsigned v0 = xcb[(size_t)s0 * 64];
                    unsigned v1 = xcb[(size_t)s1 * 64];
                    unsigned v2 = xcb[(size_t)s2 * 64];
                    unsigned v3 = xcb[(size_t)s3 * 64];
                    unsigned v4 = xcb[(size_t)s4 * 64];
                    unsigned v5 = xcb[(size_t)s5 * 64];
                    unsigned v6 = xcb[(size_t)s6 * 64];
                    unsigned v7 = xcb[(size_t)s7 * 64];
                    fmax2(m0, m1, v0); fmax2(m0, m1, v1);
                    fmax2(m0, m1, v2); fmax2(m0, m1, v3);
                    fmax2(m0, m1, v4); fmax2(m0, m1, v5);
                    fmax2(m0, m1, v6); fmax2(m0, m1, v7);
                } else {
                    if (bb + 0 < lim) fmax2(m0, m1, xcb[(size_t)s0 * 64]);
                    if (bb + 1 < lim) fmax2(m0, m1, xcb[(size_t)s1 * 64]);
                    if (bb + 2 < lim) fmax2(m0, m1, xcb[(size_t)s2 * 64]);
                    if (bb + 3 < lim) fmax2(m0, m1, xcb[(size_t)s3 * 64]);
                    if (bb + 4 < lim) fmax2(m0, m1, xcb[(size_t)s4 * 64]);
                    if (bb + 5 < lim) fmax2(m0, m1, xcb[(size_t)s5 * 64]);
                    if (bb + 6 < lim) fmax2(m0, m1, xcb[(size_t)s6 * 64]);
                    if (bb + 7 < lim) fmax2(m0, m1, xcb[(size_t)s7 * 64]);
                }
            }
            for (int i = 0; i < sN; i++) {    // per-node-cap spill (normally 0)
                int sw = spill[i];
                if ((sw & 63) == ln) fmax2(m0, m1, xcb[(size_t)(sw >> 6) * 64]);
            }
            unsigned r = 0u;
            if (lc > 0) {                     // implies node < NN
                unsigned xd = xcb[(size_t)node * 64];
                float d0 = m0 - __uint_as_float(xd << 16);
                float d1 = m1 - __uint_as_float(xd & 0xffff0000u);
                r = pack2bf(d0, d1);
            }
            *(unsigned*)&amx[ln][cb * 32 + c * 2] = r;
        }
    }
    __syncthreads();

    // ---- phase 2: MFMA GEMM (verified layout) ----
    int mm = lane & 15, g4 = lane >> 4;
    int rt = w & 1, ch = w >> 1;
    int r0 = nbase + rt * 16;
    int row = r0 + mm;
    bool rowok = row < NN;

    f32x4 acc[4];
#pragma unroll
    for (int ct = 0; ct < 4; ct++) {
        float bv = bias[ch * 64 + ct * 16 + mm];
        acc[ct] = (f32x4){bv, bv, bv, bv};
    }

    const short* xbs = (const short*)xb;
#pragma unroll
    for (int kc = 0; kc < 8; kc++) {
        int k0 = kc * 32;
        short8 a;
        if (kc < 4) {
            a = (short8){0, 0, 0, 0, 0, 0, 0, 0};
            if (rowok) a = *(const short8*)(xbs + (size_t)row * 128 + k0 + g4 * 8);
        } else {
            a = *(const short8*)&amx[rt * 16 + mm][(k0 - 128) + g4 * 8];
        }
#pragma unroll
        for (int ct = 0; ct < 4; ct++) {
            short8 bb = *(const short8*)(wt + (size_t)(ch * 64 + ct * 16 + mm) * 256 + k0 + g4 * 8);
            acc[ct] = __builtin_amdgcn_mfma_f32_16x16x32_bf16(a, bb, acc[ct], 0, 0, 0);
        }
    }

#pragma unroll
    for (int ct = 0; ct < 4; ct++) {
#pragma unroll
        for (int i = 0; i < 4; i++) {
            int rr = r0 + g4 * 4 + i;
            if (rr < NN) out[(size_t)rr * 128 + ch * 64 + ct * 16 + mm] = acc[ct][i];
        }
    }
}

// ---------------- launch ----------------

extern "C" void kernel_launch(void* const* d_in, const int* in_sizes, int n_in,
                              void* d_out, int out_size, void* d_ws, size_t ws_size,
                              hipStream_t stream) {
    const float* x = (const float*)d_in[0];
    const int* ei = (const int*)d_in[1];     // (2, E): [0..E)=src, [E..2E)=dst
    const float* W = (const float*)d_in[2];  // (256, 128) row-major
    const float* bias = (const float*)d_in[3];
    float* out = (float*)d_out;

    // Workspace layout (ints). Total = 7,226,880 ints = 28.91 MB (<= 29.40 proven).
    int* wsi = (int*)d_ws;
    int* cur    = wsi;                              // 64 (49 used)
    int* ovfn   = wsi + 64;                         // 16 (1 used)
    int* subcur = wsi + 80;                         // 1568
    int* ovfn2  = wsi + 1648;                       // 16 (1 used)
    // header padded to 2048 ints
    unsigned* ovf  = (unsigned*)(wsi + 2048);       // 800,000
    unsigned* csr  = (unsigned*)(wsi + 802048);     // NBKT*CAP = 1,204,224
    unsigned* csr2 = (unsigned*)(wsi + 2006272);    // 1568*SUBCAP = 1,204,224
    unsigned* ovf2 = (unsigned*)(wsi + 3210496);    // 800,000
    unsigned* xb   = (unsigned*)(wsi + 4010496);    // 3,200,000 (16B-aligned)
    unsigned short* wt = (unsigned short*)(wsi + 7210496);  // 32768 ush

    hipMemsetAsync(cur, 0, 2048 * sizeof(int), stream);  // all cursors + counters

    prep5_k<<<EBLK + CASTB, 256, 0, stream>>>(ei, x, W, cur, ovfn, ovf, csr, xb, wt);
    rebin_k<<<NBKT * 8, 256, 0, stream>>>(cur, csr, subcur, ovfn2, ovf2, csr2);
    fused_k<<<NBLK2, 256, 0, stream>>>(xb, subcur, ovfn, ovf, ovfn2, ovf2, csr2,
                                       (const short*)wt, bias, out);
}

// Round 11
// 188.941 us; speedup vs baseline: 1.0628x; 1.0578x over previous
//
#include <hip/hip_runtime.h>
#include <math.h>

#define NN 50000
#define NE 800000
#define CD 128
#define NBKT 49          // coarse buckets of 1024 dst nodes
#define CAP 17152        // bucket capacity (mean 16327, sd 128: +6.4 sd; overflow handled)
#define SLICE 4096       // edges per binning block
#define EBLK 196         // binning blocks
#define CASTB 2048       // cast blocks
#define NBLK2 1563       // 32-node blocks (1563*32 = 50016 >= NN)
#define SUBCAP 640       // sub-bin capacity (mean 510, sd 22.6: +5.7 sd; overflow handled)
#define OVFCAP 65536     // shared overflow list capacity
#define SSTR 800000      // stripe stride in dwords (NN*16)

typedef __attribute__((ext_vector_type(8))) short short8;
typedef __attribute__((ext_vector_type(4))) float f32x4;

// ---------------- helpers ----------------

__device__ inline unsigned pack2bf(float lo, float hi) {
    unsigned a = __float_as_uint(lo), b = __float_as_uint(hi);
    a = (a + 0x7fffu + ((a >> 16) & 1u)) >> 16;
    b = (b + 0x7fffu + ((b >> 16) & 1u)) & 0xffff0000u;
    return a | b;
}

__device__ inline unsigned short f2bf(float f) {
    unsigned u = __float_as_uint(f);
    return (unsigned short)((u + 0x7fffu + ((u >> 16) & 1u)) >> 16);
}

__device__ inline void fmax2(float& a, float& b, unsigned v) {
    a = fmaxf(a, __uint_as_float(v << 16));
    b = fmaxf(b, __uint_as_float(v & 0xffff0000u));
}

// ---------------- prep: 2-pass coarse binning (49 atomics/block) + casts ------
// Edge role: verbatim round-9/10 (proven). Cast role now writes xb in
// STRIPE-MAJOR layout: 4 physically-contiguous 3.2 MB stripes of 32 channels
// -> each stripe uses all L2 sets and fits a 4 MB per-XCD L2 (round-10's
// interleaved stripes aliased into 1/4 of the sets and thrashed).

__global__ __launch_bounds__(256) void prep5_k(const int* __restrict__ ei,
                                               const float* __restrict__ x,
                                               const float* __restrict__ W,
                                               int* __restrict__ cur,
                                               int* __restrict__ ovfn,
                                               unsigned* __restrict__ ovf,
                                               unsigned* __restrict__ csr,
                                               unsigned* __restrict__ xb,
                                               unsigned short* __restrict__ wt) {
    int b = blockIdx.x;
    int t = threadIdx.x;
    if (b < EBLK) {
        __shared__ int hist[64];
        __shared__ int curs[64];
        int e0 = b * SLICE;
        int e1 = min(NE, e0 + SLICE);
        if (t < 64) hist[t] = 0;
        __syncthreads();
        for (int e = e0 + t; e < e1; e += 256)
            atomicAdd(&hist[((unsigned)ei[NE + e]) >> 10], 1);
        __syncthreads();
        if (t < NBKT) curs[t] = atomicAdd(&cur[t], hist[t]);
        __syncthreads();
        for (int e = e0 + t; e < e1; e += 256) {
            int d = ei[NE + e];
            int s = ei[e];
            int bin = ((unsigned)d) >> 10;
            int p = atomicAdd(&curs[bin], 1);
            if (p < CAP) {
                csr[(size_t)bin * CAP + p] = ((unsigned)s << 10) | (unsigned)(d & 1023);
            } else {
                int op = atomicAdd(ovfn, 1);
                if (op < OVFCAP) ovf[op] = ((unsigned)s << 16) | (unsigned)d;
            }
        }
    } else {
        int tid0 = (b - EBLK) * 256 + t;
        for (int i = tid0; i < NN * CD / 4; i += CASTB * 256) {
            float4 v = ((const float4*)x)[i];
            int n = i >> 5, f = i & 31;            // row, float4-within-row
            uint2 r;
            r.x = pack2bf(v.x, v.y);
            r.y = pack2bf(v.z, v.w);
            *(uint2*)(xb + (size_t)(f >> 3) * SSTR + n * 16 + (f & 7) * 2) = r;
        }
        for (int i = tid0; i < 2 * CD * CD; i += CASTB * 256) {
            int n = i >> 8, k = i & 255;
            wt[(size_t)n * 256 + k] = f2bf(W[(size_t)k * 128 + n]);
        }
    }
}

// ---------------- rebin: bucket -> exact 32-node sub-lists --------------------
// 49 buckets x 8 slices; 32 global atomicAdds per block (12.5K total).
// Entry: (src << 5) | (dst & 31). Overflow shares ovf/ovfn with prep5
// (same (src<<16)|dst encoding).

__global__ __launch_bounds__(256) void rebin_k(const int* __restrict__ cur,
                                               const unsigned* __restrict__ csr,
                                               int* __restrict__ subcur,
                                               int* __restrict__ ovfn,
                                               unsigned* __restrict__ ovf,
                                               unsigned* __restrict__ csr2) {
    __shared__ int hist[32];
    __shared__ int curs[32];
    int b = blockIdx.x, t = threadIdx.x;
    int q = b >> 3, s = b & 7;
    int cnt = min(cur[q], CAP);
    int i0 = (cnt * s) >> 3, i1 = (cnt * (s + 1)) >> 3;
    if (t < 32) hist[t] = 0;
    __syncthreads();
    const unsigned* base = csr + (size_t)q * CAP;
    for (int i = i0 + t; i < i1; i += 256)
        atomicAdd(&hist[(base[i] >> 5) & 31], 1);
    __syncthreads();
    if (t < 32) curs[t] = atomicAdd(&subcur[q * 32 + t], hist[t]);
    __syncthreads();
    for (int i = i0 + t; i < i1; i += 256) {
        unsigned w = base[i];
        int sub = (int)((w >> 5) & 31u);
        int p = atomicAdd(&curs[sub], 1);
        if (p < SUBCAP) {
            csr2[(size_t)(q * 32 + sub) * SUBCAP + p] = ((w >> 10) << 5) | (w & 31u);
        } else {
            int op = atomicAdd(ovfn, 1);
            if (op < OVFCAP) ovf[op] = ((w >> 10) << 16) | (unsigned)(q * 1024 + (int)(w & 1023u));
        }
    }
}

// ---------------- gather: stripe-phased segment max -> fp32 maxdiff in OUT ----
// Grid = 4 stripes x 1563 node-blocks, stripe = bid/1563: dispatch order
// serializes stripe phases, so co-resident blocks share ONE contiguous 3.2 MB
// stripe (L2-resident per XCD -> L2-latency MSHR limit, not LLC-latency).
// Per block: build per-node LDS lists from its exact sub-list, then each
// 16-lane quarter gathers 2 nodes with 8 line-loads in flight.
// maxdiff written fp32 into out (later overwritten by gemm_k -- each gemm
// block reads only rows it itself writes, so no cross-block hazard).

__global__ __launch_bounds__(256) void gather_k(const unsigned* __restrict__ xb,
                                                const int* __restrict__ subcur,
                                                const int* __restrict__ ovfn,
                                                const unsigned* __restrict__ ovf,
                                                const unsigned* __restrict__ csr2,
                                                float* __restrict__ out) {
    __shared__ unsigned short idx[32][72];   // 64 entries; 144 B rows (16B-aligned)
    __shared__ int lcnt[32];
    __shared__ int spill[512];               // per-node-cap overflow (normally empty)
    __shared__ int spn;

    int t = threadIdx.x;
    int bid = blockIdx.x;
    int cb = bid / NBLK2;                    // stripe (dispatch-phase ordered)
    int B = bid - cb * NBLK2;
    int nbase = B * 32;

    if (t < 32) lcnt[t] = 0;
    if (t == 32) spn = 0;
    __syncthreads();

    // ---- phase 0: own sub-list -> per-node lists ----
    int cnt = min(subcur[B], SUBCAP);
    const unsigned* base = csr2 + (size_t)B * SUBCAP;
    for (int i = t; i < cnt; i += 256) {
        unsigned w = base[i];
        int ln = (int)(w & 31u);
        int s = (int)(w >> 5);
        int pos = atomicAdd(&lcnt[ln], 1);
        if (pos < 64) idx[ln][pos] = (unsigned short)s;
        else { int sp = atomicAdd(&spn, 1); if (sp < 512) spill[sp] = (s << 6) | ln; }
    }
    int ovN = min(ovfn[0], OVFCAP);          // shared overflow (normally 0)
    for (int i = t; i < ovN; i += 256) {
        unsigned w = ovf[i];
        int d = (int)(w & 0xffffu);
        if ((d >> 5) == B) {
            int ln = d & 31;
            int s = (int)(w >> 16);
            int pos = atomicAdd(&lcnt[ln], 1);
            if (pos < 64) idx[ln][pos] = (unsigned short)s;
            else { int sp = atomicAdd(&spn, 1); if (sp < 512) spill[sp] = (s << 6) | ln; }
        }
    }
    __syncthreads();

    // ---- phase 1: segment max within this stripe ----
    int w4 = t >> 6, lane = t & 63;
    int q4 = lane >> 4, c = lane & 15;
    const unsigned* xs = xb + (size_t)cb * SSTR + c;   // lane's dword in stripe rows
    int sN = min(spn, 512);
#pragma unroll 1
    for (int j = 0; j < 2; j++) {
        int ln = w4 * 8 + j * 4 + q4;
        int node = nbase + ln;
        int lc = lcnt[ln];
        int lim = min(lc, 64);
        float m0 = -INFINITY, m1 = -INFINITY;

        for (int bb = 0; bb < lim; bb += 8) {
            uint4 pk = *(const uint4*)&idx[ln][bb];
            int s0 = (int)(pk.x & 0xffffu), s1 = (int)(pk.x >> 16);
            int s2 = (int)(pk.y & 0xffffu), s3 = (int)(pk.y >> 16);
            int s4 = (int)(pk.z & 0xffffu), s5 = (int)(pk.z >> 16);
            int s6 = (int)(pk.w & 0xffffu), s7 = (int)(pk.w >> 16);
            if (bb + 8 <= lim) {              // fast path: 8 line-loads in flight
                unsigned v0 = xs[(size_t)s0 * 16];
                unsigned v1 = xs[(size_t)s1 * 16];
                unsigned v2 = xs[(size_t)s2 * 16];
                unsigned v3 = xs[(size_t)s3 * 16];
                unsigned v4 = xs[(size_t)s4 * 16];
                unsigned v5 = xs[(size_t)s5 * 16];
                unsigned v6 = xs[(size_t)s6 * 16];
                unsigned v7 = xs[(size_t)s7 * 16];
                fmax2(m0, m1, v0); fmax2(m0, m1, v1);
                fmax2(m0, m1, v2); fmax2(m0, m1, v3);
                fmax2(m0, m1, v4); fmax2(m0, m1, v5);
                fmax2(m0, m1, v6); fmax2(m0, m1, v7);
            } else {
                if (bb + 0 < lim) fmax2(m0, m1, xs[(size_t)s0 * 16]);
                if (bb + 1 < lim) fmax2(m0, m1, xs[(size_t)s1 * 16]);
                if (bb + 2 < lim) fmax2(m0, m1, xs[(size_t)s2 * 16]);
                if (bb + 3 < lim) fmax2(m0, m1, xs[(size_t)s3 * 16]);
                if (bb + 4 < lim) fmax2(m0, m1, xs[(size_t)s4 * 16]);
                if (bb + 5 < lim) fmax2(m0, m1, xs[(size_t)s5 * 16]);
                if (bb + 6 < lim) fmax2(m0, m1, xs[(size_t)s6 * 16]);
                if (bb + 7 < lim) fmax2(m0, m1, xs[(size_t)s7 * 16]);
            }
        }
        for (int i = 0; i < sN; i++) {        // per-node-cap spill (normally 0)
            int sw = spill[i];
            if ((sw & 63) == ln) fmax2(m0, m1, xs[(size_t)(sw >> 6) * 16]);
        }
        if (node < NN) {
            float2 r = make_float2(0.f, 0.f);
            if (lc > 0) {
                unsigned xd = xs[(size_t)node * 16];
                r.x = m0 - __uint_as_float(xd << 16);
                r.y = m1 - __uint_as_float(xd & 0xffff0000u);
            }
            *(float2*)(out + (size_t)node * 128 + cb * 32 + c * 2) = r;
        }
    }
}

// ---------------- GEMM: out = [x | maxdiff] @ Wt^T + bias --------------------
// Round-3 verified structure (4 waves, 16 rows x 128 cols each, 8 col-tiles).
// A-top from stripe-major bf16 xb; A-bottom from fp32 maxdiff currently in
// out (same RNE pack -> bit-identical to prior mdb path). All A reads precede
// all stores in wave program order; waves touch disjoint rows.

__global__ __launch_bounds__(256) void gemm_k(const unsigned* __restrict__ xb,
                                              const short* __restrict__ wt,
                                              const float* __restrict__ bias,
                                              float* __restrict__ out) {
    int t = threadIdx.x;
    int w = t >> 6, lane = t & 63;
    int m = lane & 15, g = lane >> 4;
    int r0 = blockIdx.x * 64 + w * 16;
    int row = r0 + m;
    bool rowok = row < NN;

    f32x4 acc[8];
#pragma unroll
    for (int ct = 0; ct < 8; ct++) {
        float bv = bias[ct * 16 + m];
        acc[ct] = (f32x4){bv, bv, bv, bv};
    }

#pragma unroll
    for (int kc = 0; kc < 8; kc++) {
        int k0 = kc * 32;
        short8 a = (short8){0, 0, 0, 0, 0, 0, 0, 0};
        if (rowok) {
            if (kc < 4) {
                a = *(const short8*)(xb + (size_t)kc * SSTR + (size_t)row * 16 + g * 4);
            } else {
                const float* p = out + (size_t)row * 128 + (k0 - 128) + g * 8;
                float4 u = *(const float4*)p;
                float4 v = *(const float4*)(p + 4);
                a = (short8){(short)f2bf(u.x), (short)f2bf(u.y), (short)f2bf(u.z), (short)f2bf(u.w),
                             (short)f2bf(v.x), (short)f2bf(v.y), (short)f2bf(v.z), (short)f2bf(v.w)};
            }
        }
#pragma unroll
        for (int ct = 0; ct < 8; ct++) {
            short8 b = *(const short8*)(wt + (size_t)(ct * 16 + m) * 256 + k0 + g * 8);
            acc[ct] = __builtin_amdgcn_mfma_f32_16x16x32_bf16(a, b, acc[ct], 0, 0, 0);
        }
    }

    __syncthreads();   // belt-and-braces: all maxdiff reads drained before stores

#pragma unroll
    for (int ct = 0; ct < 8; ct++) {
#pragma unroll
        for (int i = 0; i < 4; i++) {
            int rr = r0 + g * 4 + i;
            if (rr < NN) out[(size_t)rr * 128 + ct * 16 + m] = acc[ct][i];
        }
    }
}

// ---------------- launch ----------------

extern "C" void kernel_launch(void* const* d_in, const int* in_sizes, int n_in,
                              void* d_out, int out_size, void* d_ws, size_t ws_size,
                              hipStream_t stream) {
    const float* x = (const float*)d_in[0];
    const int* ei = (const int*)d_in[1];     // (2, E): [0..E)=src, [E..2E)=dst
    const float* W = (const float*)d_in[2];  // (256, 128) row-major
    const float* bias = (const float*)d_in[3];
    float* out = (float*)d_out;

    // Workspace layout (ints). Total = 5,127,936 ints = 20.51 MB.
    int* wsi = (int*)d_ws;
    int* cur    = wsi;                              // 64 (49 used)
    int* ovfn   = wsi + 64;                         // 16 (1 used)
    int* subcur = wsi + 80;                         // 1568
    // header padded to 2048 ints
    unsigned* ovf  = (unsigned*)(wsi + 2048);       // 65,536 (shared overflow list)
    unsigned* csr  = (unsigned*)(wsi + 67584);      // NBKT*CAP = 840,448
    unsigned* csr2 = (unsigned*)(wsi + 908032);     // 1568*SUBCAP = 1,003,520
    unsigned* xb   = (unsigned*)(wsi + 1911552);    // 4 stripes x 800,000 (16B-aligned)
    unsigned short* wt = (unsigned short*)(wsi + 5111552);  // 32768 ush

    hipMemsetAsync(cur, 0, 2048 * sizeof(int), stream);  // all cursors + counters

    prep5_k<<<EBLK + CASTB, 256, 0, stream>>>(ei, x, W, cur, ovfn, ovf, csr, xb, wt);
    rebin_k<<<NBKT * 8, 256, 0, stream>>>(cur, csr, subcur, ovfn, ovf, csr2);
    gather_k<<<NBLK2 * 4, 256, 0, stream>>>(xb, subcur, ovfn, ovf, csr2, out);
    gemm_k<<<(NN + 63) / 64, 256, 0, stream>>>(xb, (const short*)wt, bias, out);
}